// Round 8
// baseline (187.166 us; speedup 1.0000x reference)
//
#include <hip/hip_runtime.h>
#include <cstdint>

typedef float   f32x4  __attribute__((ext_vector_type(4)));
typedef __bf16  bf16x4 __attribute__((ext_vector_type(4)));
typedef __bf16  bf16x8 __attribute__((ext_vector_type(8)));

#if __has_builtin(__builtin_amdgcn_exp2f)
#define EXP2F(x) __builtin_amdgcn_exp2f(x)
#else
#define EXP2F(x) exp2f(x)
#endif

#define BT_TOTAL 512
#define NNODES 170
#define CDIM 128
#define HEADS 8
#define HDIM 16
#define SLAB (NNODES*HDIM)           // 2720
#define NPAD 176                     // V^T row stride
#define VSLAB (HDIM*NPAD)            // 2816
#define QKV_ELEMS ((size_t)BT_TOTAL*HEADS*SLAB)
#define WPAD 136                     // LDS W row stride
#define S2L2E 0.12753851f            // log2(e)/sqrt(128), folded into Wq/bq
#define PROWS 340                    // rows per bt-pair block
#define PTILES 22                    // ceil(340/16)

// ---------------------------------------------------------------- W -> bf16, k-swizzled
// wbf[mat][c][kk*32 + l4*8 + j] = W[mat][c][kk*32 + l4*4 + (j&3) + 16*(j>>2)]
__global__ __launch_bounds__(256) void wconv_kernel(const float* __restrict__ wq,
                                                    const float* __restrict__ wk,
                                                    const float* __restrict__ wv,
                                                    const float* __restrict__ wo,
                                                    __bf16* __restrict__ wbf) {
    int idx = blockIdx.x * 256 + threadIdx.x;
    if (idx >= 4 * 16384) return;
    int mat = idx >> 14, rem = idx & 16383;
    int c = rem >> 7, o = rem & 127;
    int kk = o >> 5, l4 = (o & 31) >> 3, j = o & 7;
    int col = kk * 32 + l4 * 4 + (j & 3) + 16 * (j >> 2);
    const float* W = (mat == 0) ? wq : (mat == 1) ? wk : (mat == 2) ? wv : wo;
    float scale = (mat == 0) ? S2L2E : 1.0f;
    wbf[idx] = (__bf16)(W[c * 128 + col] * scale);
}

// ---------------------------------------------------------------- QKV projection, persistent bt-pair blocks
// grid = 3 * 256 blocks x 256 thr (4 waves). Block = (iid, bt-pair) = 340 rows.
// One W-stage + one barrier, then a barrier-free steady loop: compute(t) || prefetch(t+8).
__global__ __launch_bounds__(256, 4) void qkv_kernel(const float* __restrict__ qin,
    const float* __restrict__ kin, const float* __restrict__ vin,
    const __bf16* __restrict__ wbf,
    const float* __restrict__ bq, const float* __restrict__ bk, const float* __restrict__ bv,
    __bf16* __restrict__ qws, __bf16* __restrict__ kws, __bf16* __restrict__ vt) {
    __shared__ __bf16 Wl[128 * WPAD];
    int t = threadIdx.x;
    int bid = blockIdx.x;
    int iid = bid >> 8;                 // 0=q, 1=k, 2=v
    int pr  = bid & 255;                // bt-pair index
    const float* X    = (iid == 0) ? qin : (iid == 1) ? kin : vin;
    const float* bias = (iid == 0) ? bq  : (iid == 1) ? bk  : bv;
    float wscale = (iid == 0) ? S2L2E : 1.0f;
    const __bf16* wb = wbf + iid * 16384;
    #pragma unroll
    for (int i = 0; i < 8; ++i) {
        int idx = i * 256 + t;
        int c = idx >> 4, x = (idx & 15) * 8;
        *(bf16x8*)&Wl[c * WPAD + x] = *(const bf16x8*)&wb[idx * 8];
    }
    __syncthreads();

    int w = t >> 6, lane = t & 63, li = lane & 15, l4 = lane >> 4;
    const f32x4 zf = {0.f, 0.f, 0.f, 0.f};
    size_t gbase = (size_t)pr * PROWS;

    auto loadA = [&](f32x4* A, int tile) {
        int r = tile * 16 + li;
        bool v = r < PROWS;
        const float* xr = X + (gbase + r) * CDIM;
        #pragma unroll
        for (int kk = 0; kk < 4; ++kk) {
            A[2 * kk]     = v ? *(const f32x4*)(xr + kk * 32 + l4 * 4)      : zf;
            A[2 * kk + 1] = v ? *(const f32x4*)(xr + kk * 32 + l4 * 4 + 16) : zf;
        }
    };

    auto compute = [&](const f32x4* A, int tile) {
        f32x4 acc[8] = {};
        #pragma unroll
        for (int kk = 0; kk < 4; ++kk) {
            f32x4 a0 = A[2 * kk], a1 = A[2 * kk + 1];
            bf16x8 a = { (__bf16)a0[0], (__bf16)a0[1], (__bf16)a0[2], (__bf16)a0[3],
                         (__bf16)a1[0], (__bf16)a1[1], (__bf16)a1[2], (__bf16)a1[3] };
            #pragma unroll
            for (int nt = 0; nt < 8; ++nt) {
                bf16x8 b = *(const bf16x8*)&Wl[(nt * 16 + li) * WPAD + kk * 32 + l4 * 8];
                if (iid < 2)
                    acc[nt] = __builtin_amdgcn_mfma_f32_16x16x32_bf16(b, a, acc[nt], 0, 0, 0);
                else
                    acc[nt] = __builtin_amdgcn_mfma_f32_16x16x32_bf16(a, b, acc[nt], 0, 0, 0);
            }
        }
        if (iid < 2) {
            int r = tile * 16 + li;
            if (r < PROWS) {
                int g = (int)gbase + r;
                int bt = g / NNODES, n = g - bt * NNODES;
                __bf16* dst = ((iid == 0) ? qws : kws) + (size_t)bt * HEADS * SLAB;
                #pragma unroll
                for (int nt = 0; nt < 8; ++nt) {      // h=nt, d=l4*4+r
                    f32x4 b4 = *(const f32x4*)&bias[nt * 16 + l4 * 4];
                    f32x4 ov = acc[nt] + b4 * wscale;
                    bf16x4 o4 = { (__bf16)ov[0], (__bf16)ov[1], (__bf16)ov[2], (__bf16)ov[3] };
                    *(bf16x4*)&dst[(size_t)nt * SLAB + n * HDIM + l4 * 4] = o4;
                }
            }
        } else {
            int r0 = tile * 16 + l4 * 4;
            int g0 = (int)gbase + r0;
            if (r0 + 3 < PROWS) {
                int bt0 = g0 / NNODES, n0 = g0 - bt0 * NNODES;
                if (n0 <= NNODES - 4) {
                    #pragma unroll
                    for (int nt = 0; nt < 8; ++nt) {  // h=nt, d=li
                        float bval = bias[nt * 16 + li];
                        bf16x4 o4 = { (__bf16)(acc[nt][0] + bval), (__bf16)(acc[nt][1] + bval),
                                      (__bf16)(acc[nt][2] + bval), (__bf16)(acc[nt][3] + bval) };
                        *(bf16x4*)&vt[((size_t)(bt0 * HEADS + nt)) * VSLAB + li * NPAD + n0] = o4;
                    }
                } else {
                    #pragma unroll
                    for (int nt = 0; nt < 8; ++nt) {
                        float bval = bias[nt * 16 + li];
                        #pragma unroll
                        for (int rr = 0; rr < 4; ++rr) {
                            int g = g0 + rr;
                            int bt = g / NNODES, n = g - bt * NNODES;
                            vt[((size_t)(bt * HEADS + nt)) * VSLAB + li * NPAD + n] = (__bf16)(acc[nt][rr] + bval);
                        }
                    }
                }
            } else {
                #pragma unroll
                for (int nt = 0; nt < 8; ++nt) {
                    float bval = bias[nt * 16 + li];
                    #pragma unroll
                    for (int rr = 0; rr < 4; ++rr) {
                        if (r0 + rr < PROWS) {
                            int g = g0 + rr;
                            int bt = g / NNODES, n = g - bt * NNODES;
                            vt[((size_t)(bt * HEADS + nt)) * VSLAB + li * NPAD + n] = (__bf16)(acc[nt][rr] + bval);
                        }
                    }
                }
            }
        }
    };

    // steady-state ping-pong: compute(t) while 2 tiles of loads stay in flight.
    f32x4 A0[8], A1[8];
    loadA(A0, w);
    loadA(A1, w + 4);
    for (int tc = w; tc < PTILES; tc += 8) {
        compute(A0, tc);
        loadA(A0, tc + 8);              // no-op (exec-masked) past the end
        if (tc + 4 >= PTILES) break;
        compute(A1, tc + 4);
        loadA(A1, tc + 12);
    }
}

// ---------------------------------------------------------------- attention core (round-5, proven)
// 4 independent wave-units per 256-thread block; unit = (bt, h, q-half).
// O stored in k-swizzled column order for oproj's contiguous bf16x8 A-loads.
__global__ __launch_bounds__(256) void attn_kernel(const __bf16* __restrict__ qws,
                                                   const __bf16* __restrict__ kws,
                                                   const __bf16* __restrict__ vt,
                                                   __bf16* __restrict__ ows) {
    int unit = blockIdx.x * 4 + (threadIdx.x >> 6);
    int half = unit & 1, bh = unit >> 1;
    int bt = bh >> 3, h = bh & 7;
    int lane = threadIdx.x & 63, li = lane & 15, l4 = lane >> 4;
    const __bf16* qb  = qws + ((size_t)(bt * HEADS + h)) * SLAB;
    const __bf16* kb  = kws + ((size_t)(bt * HEADS + h)) * SLAB;
    const __bf16* vtb = vt  + ((size_t)(bt * HEADS + h)) * VSLAB;
    __bf16* ob = ows + (size_t)bt * NNODES * CDIM + (h >> 1) * 32 + (h & 1) * 4;
    const __bf16 bz = (__bf16)0.0f;
    const bf16x4 z4 = {bz, bz, bz, bz};
    const f32x4 zf = {0.f, 0.f, 0.f, 0.f};

    bf16x4 kf[11];
    #pragma unroll
    for (int tt = 0; tt < 11; ++tt)
        kf[tt] = *(const bf16x4*)&kb[(tt * 16 + li) * HDIM + l4 * 4];

    bf16x8 vf[6];
    #pragma unroll
    for (int s = 0; s < 5; ++s) {
        bf16x4 a = *(const bf16x4*)&vtb[li * NPAD + 32 * s + 4 * l4];
        bf16x4 b = *(const bf16x4*)&vtb[li * NPAD + 32 * s + 4 * l4 + 16];
        vf[s] = __builtin_shufflevector(a, b, 0, 1, 2, 3, 4, 5, 6, 7);
    }
    {
        bf16x4 a = *(const bf16x4*)&vtb[li * NPAD + 160 + 4 * l4];
        bf16x8 v5 = { (160 + 4 * l4 + 0 < NNODES) ? a[0] : bz,
                      (160 + 4 * l4 + 1 < NNODES) ? a[1] : bz,
                      (160 + 4 * l4 + 2 < NNODES) ? a[2] : bz,
                      (160 + 4 * l4 + 3 < NNODES) ? a[3] : bz,
                      bz, bz, bz, bz };
        vf[5] = v5;
    }

    int q0 = half ? 6 : 0;
    int qn = half ? 5 : 6;
    for (int qi = 0; qi < qn; ++qi) {
        int qc = q0 + qi;
        bf16x4 qv = *(const bf16x4*)&qb[(qc * 16 + li) * HDIM + l4 * 4];
        bf16x8 qf = __builtin_shufflevector(qv, z4, 0, 1, 2, 3, 4, 5, 6, 7);
        bf16x4 ph[11];
        f32x4 s4 = zf;
        #pragma unroll
        for (int tt = 0; tt < 11; ++tt) {
            bf16x8 a = __builtin_shufflevector(kf[tt], z4, 0, 1, 2, 3, 4, 5, 6, 7);
            f32x4 e = __builtin_amdgcn_mfma_f32_16x16x32_bf16(a, qf, zf, 0, 0, 0);
            if (tt == 10) {   // select BEFORE exp2: NaN-safe for unwritten K rows
                #pragma unroll
                for (int r = 0; r < 4; ++r)
                    e[r] = (160 + l4 * 4 + r < NNODES) ? e[r] : -1.0e30f;
            }
            f32x4 p;
            p[0] = EXP2F(e[0]); p[1] = EXP2F(e[1]);
            p[2] = EXP2F(e[2]); p[3] = EXP2F(e[3]);
            s4 += p;
            ph[tt] = __builtin_convertvector(p, bf16x4);
        }
        float sum = (s4[0] + s4[1]) + (s4[2] + s4[3]);
        sum += __shfl_xor(sum, 16);
        sum += __shfl_xor(sum, 32);
        float inv = 1.0f / sum;
        f32x4 o0 = zf, o1 = zf;
        o0 = __builtin_amdgcn_mfma_f32_16x16x32_bf16(vf[0],
                __builtin_shufflevector(ph[0], ph[1], 0,1,2,3,4,5,6,7), o0, 0,0,0);
        o1 = __builtin_amdgcn_mfma_f32_16x16x32_bf16(vf[1],
                __builtin_shufflevector(ph[2], ph[3], 0,1,2,3,4,5,6,7), o1, 0,0,0);
        o0 = __builtin_amdgcn_mfma_f32_16x16x32_bf16(vf[2],
                __builtin_shufflevector(ph[4], ph[5], 0,1,2,3,4,5,6,7), o0, 0,0,0);
        o1 = __builtin_amdgcn_mfma_f32_16x16x32_bf16(vf[3],
                __builtin_shufflevector(ph[6], ph[7], 0,1,2,3,4,5,6,7), o1, 0,0,0);
        o0 = __builtin_amdgcn_mfma_f32_16x16x32_bf16(vf[4],
                __builtin_shufflevector(ph[8], ph[9], 0,1,2,3,4,5,6,7), o0, 0,0,0);
        o1 = __builtin_amdgcn_mfma_f32_16x16x32_bf16(vf[5],
                __builtin_shufflevector(ph[10], z4,    0,1,2,3,4,5,6,7), o1, 0,0,0);
        f32x4 o = (o0 + o1) * inv;
        int q = qc * 16 + li;
        if (q < NNODES) {
            bf16x4 ov = { (__bf16)o[0], (__bf16)o[1], (__bf16)o[2], (__bf16)o[3] };
            *(bf16x4*)&ob[(size_t)q * CDIM + l4 * 8] = ov;
        }
    }
}

// ---------------------------------------------------------------- output projection (round-5, proven)
__global__ __launch_bounds__(512) void oproj_kernel(const __bf16* __restrict__ ows,
                                                    const __bf16* __restrict__ wbf,
                                                    const float* __restrict__ bo,
                                                    float* __restrict__ out) {
    __shared__ __bf16 Wl[128 * WPAD];
    int t = threadIdx.x;
    int bt = blockIdx.x;
    const __bf16* wo = wbf + 3 * 16384;
    #pragma unroll
    for (int i = 0; i < 4; ++i) {
        int idx = i * 512 + t;
        int c = idx >> 4, x = (idx & 15) * 8;
        *(bf16x8*)&Wl[c * WPAD + x] = *(const bf16x8*)&wo[idx * 8];
    }
    __syncthreads();

    int w = t >> 6, lane = t & 63, li = lane & 15, l4 = lane >> 4;
    const bf16x8 z8 = {};

    auto loadO = [&](bf16x8* A, int tile) {
        int mrow = tile * 16 + li;
        bool v = mrow < NNODES;
        const __bf16* ar = ows + ((size_t)(bt * NNODES + mrow)) * CDIM;
        #pragma unroll
        for (int kk = 0; kk < 4; ++kk)
            A[kk] = v ? *(const bf16x8*)(ar + kk * 32 + l4 * 8) : z8;
    };
    auto computeO = [&](const bf16x8* A, int tile) {
        f32x4 acc[8] = {};
        #pragma unroll
        for (int kk = 0; kk < 4; ++kk) {
            #pragma unroll
            for (int nt = 0; nt < 8; ++nt) {
                bf16x8 b = *(const bf16x8*)&Wl[(nt * 16 + li) * WPAD + kk * 32 + l4 * 8];
                acc[nt] = __builtin_amdgcn_mfma_f32_16x16x32_bf16(b, A[kk], acc[nt], 0, 0, 0);
            }
        }
        int n = tile * 16 + li;
        if (n < NNODES) {
            float* orow = out + ((size_t)bt * NNODES + n) * CDIM;
            #pragma unroll
            for (int nt = 0; nt < 8; ++nt) {
                f32x4 b4 = *(const f32x4*)&bo[nt * 16 + l4 * 4];
                *(f32x4*)&orow[nt * 16 + l4 * 4] = acc[nt] + b4;
            }
        }
    };

    bf16x8 A0[4], A1[4];
    loadO(A0, w);
    if (w < 3) loadO(A1, w + 8);
    computeO(A0, w);
    if (w < 3) computeO(A1, w + 8);
}

// ---------------------------------------------------------------- launch
extern "C" void kernel_launch(void* const* d_in, const int* in_sizes, int n_in,
                              void* d_out, int out_size, void* d_ws, size_t ws_size,
                              hipStream_t stream) {
    const float* values = (const float*)d_in[0];
    const float* keys   = (const float*)d_in[1];
    const float* query  = (const float*)d_in[2];
    const float* Wv = (const float*)d_in[3];
    const float* bv = (const float*)d_in[4];
    const float* Wk = (const float*)d_in[5];
    const float* bk = (const float*)d_in[6];
    const float* Wq = (const float*)d_in[7];
    const float* bq = (const float*)d_in[8];
    const float* Wo = (const float*)d_in[9];
    const float* bo = (const float*)d_in[10];
    float* out = (float*)d_out;

    __bf16* qws = (__bf16*)d_ws;
    __bf16* kws = qws + QKV_ELEMS;
    __bf16* ows = kws + QKV_ELEMS;
    __bf16* wbf = ows + QKV_ELEMS;            // 4 x 16384 bf16, swizzled (+scaled Wq)
    __bf16* vt  = (__bf16*)d_out;             // V^T scratch in d_out, consumed by attn
                                              // before oproj overwrites with final out

    hipLaunchKernelGGL(wconv_kernel, dim3(256),  dim3(256), 0, stream, Wq, Wk, Wv, Wo, wbf);
    hipLaunchKernelGGL(qkv_kernel,   dim3(768),  dim3(256), 0, stream,
                       query, keys, values, wbf, bq, bk, bv, qws, kws, vt);
    hipLaunchKernelGGL(attn_kernel,  dim3(2048), dim3(256), 0, stream, qws, kws, vt, ows);
    hipLaunchKernelGGL(oproj_kernel, dim3(512),  dim3(512), 0, stream, ows, wbf, bo, out);
}

// Round 9
// 93.180 us; speedup vs baseline: 2.0086x; 2.0086x over previous
//
#include <hip/hip_runtime.h>
#include <cstdint>

typedef float   f32x4  __attribute__((ext_vector_type(4)));
typedef __bf16  bf16x4 __attribute__((ext_vector_type(4)));
typedef __bf16  bf16x8 __attribute__((ext_vector_type(8)));

#if __has_builtin(__builtin_amdgcn_exp2f)
#define EXP2F(x) __builtin_amdgcn_exp2f(x)
#else
#define EXP2F(x) exp2f(x)
#endif

#define BT_TOTAL 512
#define NNODES 170
#define CDIM 128
#define HEADS 8
#define HDIM 16
#define SLAB (NNODES*HDIM)           // 2720
#define NPAD 172                     // V^T row stride
#define VSLAB (HDIM*NPAD)            // 2752
#define QKV_ELEMS ((size_t)BT_TOTAL*HEADS*SLAB)
#define S2L2E 0.12753851f            // log2(e)/sqrt(128), folded into Wq/bq

// ---------------------------------------------------------------- fused QKV projection
// iid 0=q -> qws [bt][h][n][d]   (swapped mfma -> 8B vector stores; W,b scaled)
// iid 1=k -> kws [bt][h][n][d]   (swapped)
// iid 2=v -> vt  [bt][h][d][NPAD] (unswapped; vector stores along n)
__global__ __launch_bounds__(512) void qkv_kernel(const float* __restrict__ qin,
    const float* __restrict__ kin, const float* __restrict__ vin,
    const float* __restrict__ Wq, const float* __restrict__ Wk, const float* __restrict__ Wv,
    const float* __restrict__ bq, const float* __restrict__ bk, const float* __restrict__ bv,
    __bf16* __restrict__ qws, __bf16* __restrict__ kws, __bf16* __restrict__ vt) {
    __shared__ __bf16 Wl[128 * 132];
    int t = threadIdx.x;
    int iid = blockIdx.x / BT_TOTAL;
    int bt  = blockIdx.x % BT_TOTAL;
    const float* X    = (iid == 0) ? qin : (iid == 1) ? kin : vin;
    const float* W    = (iid == 0) ? Wq  : (iid == 1) ? Wk  : Wv;
    const float* bias = (iid == 0) ? bq  : (iid == 1) ? bk  : bv;
    float wscale = (iid == 0) ? S2L2E : 1.0f;
    #pragma unroll
    for (int i = 0; i < 8; ++i) {
        int idx = i * 512 + t;
        int r = idx >> 5, c = (idx & 31) * 4;
        f32x4 w4 = *(const f32x4*)&W[r * 128 + c];
        bf16x4 wb = { (__bf16)(w4[0] * wscale), (__bf16)(w4[1] * wscale),
                      (__bf16)(w4[2] * wscale), (__bf16)(w4[3] * wscale) };
        *(bf16x4*)&Wl[r * 132 + c] = wb;
    }
    __syncthreads();

    int w = t >> 6, lane = t & 63, li = lane & 15, l4 = lane >> 4;
    f32x4 zf = {0.f, 0.f, 0.f, 0.f};
    for (int mt = 0; mt < 2; ++mt) {
        int tbase = mt * 128 + w * 16;
        if (tbase >= NNODES) break;              // wave-uniform
        int mrow = tbase + li;
        bool mvalid = mrow < NNODES;
        const float* xrow = X + ((size_t)(bt * NNODES + mrow)) * CDIM;
        f32x4 acc[8] = {};
        #pragma unroll
        for (int kk = 0; kk < 4; ++kk) {
            int kb = kk * 32 + l4 * 4;
            f32x4 a0 = mvalid ? *(const f32x4*)(xrow + kb)      : zf;
            f32x4 a1 = mvalid ? *(const f32x4*)(xrow + kb + 16) : zf;
            bf16x8 a = { (__bf16)a0[0], (__bf16)a0[1], (__bf16)a0[2], (__bf16)a0[3],
                         (__bf16)a1[0], (__bf16)a1[1], (__bf16)a1[2], (__bf16)a1[3] };
            if (iid < 2) {
                #pragma unroll
                for (int nt = 0; nt < 8; ++nt) {
                    int c = nt * 16 + li;
                    bf16x4 b0 = *(const bf16x4*)&Wl[c * 132 + kb];
                    bf16x4 b1 = *(const bf16x4*)&Wl[c * 132 + kb + 16];
                    bf16x8 b = __builtin_shufflevector(b0, b1, 0, 1, 2, 3, 4, 5, 6, 7);
                    // swapped: C^T = W * X^T -> col(li)=n, row(4*l4+r)=channel
                    acc[nt] = __builtin_amdgcn_mfma_f32_16x16x32_bf16(b, a, acc[nt], 0, 0, 0);
                }
            } else {
                #pragma unroll
                for (int nt = 0; nt < 8; ++nt) {
                    int c = nt * 16 + li;
                    bf16x4 b0 = *(const bf16x4*)&Wl[c * 132 + kb];
                    bf16x4 b1 = *(const bf16x4*)&Wl[c * 132 + kb + 16];
                    bf16x8 b = __builtin_shufflevector(b0, b1, 0, 1, 2, 3, 4, 5, 6, 7);
                    // unswapped: col(li)=channel, row(4*l4+r)=n
                    acc[nt] = __builtin_amdgcn_mfma_f32_16x16x32_bf16(a, b, acc[nt], 0, 0, 0);
                }
            }
        }
        if (iid < 2) {
            __bf16* outb = ((iid == 0) ? qws : kws) + ((size_t)bt * HEADS) * SLAB;
            int n = tbase + li;
            if (n < NNODES) {
                #pragma unroll
                for (int nt = 0; nt < 8; ++nt) {
                    // channels c = nt*16 + l4*4 + r  ->  h = nt, d = l4*4 + r
                    f32x4 b4 = *(const f32x4*)&bias[nt * 16 + l4 * 4];
                    f32x4 o = acc[nt] + b4 * wscale;
                    bf16x4 o4 = { (__bf16)o[0], (__bf16)o[1], (__bf16)o[2], (__bf16)o[3] };
                    *(bf16x4*)&outb[(size_t)nt * SLAB + n * HDIM + l4 * 4] = o4;
                }
            }
        } else {
            __bf16* outb = vt + ((size_t)bt * HEADS) * VSLAB;
            int n0 = tbase + l4 * 4;
            #pragma unroll
            for (int nt = 0; nt < 8; ++nt) {
                int c = nt * 16 + li;              // h = nt, d = li
                float bval = bias[c];
                __bf16* dst = outb + (size_t)nt * VSLAB + li * NPAD + n0;
                if (n0 + 3 < NNODES) {
                    bf16x4 o4 = { (__bf16)(acc[nt][0] + bval), (__bf16)(acc[nt][1] + bval),
                                  (__bf16)(acc[nt][2] + bval), (__bf16)(acc[nt][3] + bval) };
                    *(bf16x4*)dst = o4;
                } else {
                    #pragma unroll
                    for (int r = 0; r < 4; ++r)
                        if (n0 + r < NNODES) dst[r] = (__bf16)(acc[nt][r] + bval);
                }
            }
        }
    }
}

// ---------------------------------------------------------------- attention core
// 4 independent wave-units per 256-thread block; unit = (bt, h, q-half).
__global__ __launch_bounds__(256) void attn_kernel(const __bf16* __restrict__ qws,
                                                   const __bf16* __restrict__ kws,
                                                   const __bf16* __restrict__ vt,
                                                   __bf16* __restrict__ ows) {
    int unit = blockIdx.x * 4 + (threadIdx.x >> 6);
    int half = unit & 1, bh = unit >> 1;
    int bt = bh >> 3, h = bh & 7;
    int lane = threadIdx.x & 63, li = lane & 15, l4 = lane >> 4;
    const __bf16* qb  = qws + ((size_t)(bt * HEADS + h)) * SLAB;
    const __bf16* kb  = kws + ((size_t)(bt * HEADS + h)) * SLAB;
    const __bf16* vtb = vt  + ((size_t)(bt * HEADS + h)) * VSLAB;
    __bf16* ob = ows + (size_t)bt * NNODES * CDIM + h * HDIM;
    const __bf16 bz = (__bf16)0.0f;
    const bf16x4 z4 = {bz, bz, bz, bz};
    const f32x4 zf = {0.f, 0.f, 0.f, 0.f};

    bf16x4 kf[11];
    #pragma unroll
    for (int tt = 0; tt < 11; ++tt)
        kf[tt] = *(const bf16x4*)&kb[(tt * 16 + li) * HDIM + l4 * 4];

    bf16x8 vf[6];
    #pragma unroll
    for (int s = 0; s < 5; ++s) {
        bf16x4 a = *(const bf16x4*)&vtb[li * NPAD + 32 * s + 4 * l4];
        bf16x4 b = *(const bf16x4*)&vtb[li * NPAD + 32 * s + 4 * l4 + 16];
        vf[s] = __builtin_shufflevector(a, b, 0, 1, 2, 3, 4, 5, 6, 7);
    }
    {
        bf16x4 a = *(const bf16x4*)&vtb[li * NPAD + 160 + 4 * l4];
        bf16x8 v5 = { (160 + 4 * l4 + 0 < NNODES) ? a[0] : bz,
                      (160 + 4 * l4 + 1 < NNODES) ? a[1] : bz,
                      (160 + 4 * l4 + 2 < NNODES) ? a[2] : bz,
                      (160 + 4 * l4 + 3 < NNODES) ? a[3] : bz,
                      bz, bz, bz, bz };
        vf[5] = v5;
    }
    f32x4 mk = { (160 + l4 * 4 + 0 < NNODES) ? 1.f : 0.f,
                 (160 + l4 * 4 + 1 < NNODES) ? 1.f : 0.f,
                 (160 + l4 * 4 + 2 < NNODES) ? 1.f : 0.f,
                 (160 + l4 * 4 + 3 < NNODES) ? 1.f : 0.f };

    int q0 = half ? 6 : 0;
    int qn = half ? 5 : 6;
    for (int qi = 0; qi < qn; ++qi) {
        int qc = q0 + qi;
        bf16x4 qv = *(const bf16x4*)&qb[(qc * 16 + li) * HDIM + l4 * 4];
        bf16x8 qf = __builtin_shufflevector(qv, z4, 0, 1, 2, 3, 4, 5, 6, 7);
        bf16x4 ph[11];
        f32x4 s4 = zf;
        #pragma unroll
        for (int tt = 0; tt < 11; ++tt) {
            bf16x8 a = __builtin_shufflevector(kf[tt], z4, 0, 1, 2, 3, 4, 5, 6, 7);
            f32x4 e = __builtin_amdgcn_mfma_f32_16x16x32_bf16(a, qf, zf, 0, 0, 0);
            f32x4 p;
            p[0] = EXP2F(e[0]); p[1] = EXP2F(e[1]);
            p[2] = EXP2F(e[2]); p[3] = EXP2F(e[3]);
            if (tt == 10) p *= mk;
            s4 += p;
            ph[tt] = __builtin_convertvector(p, bf16x4);
        }
        float sum = (s4[0] + s4[1]) + (s4[2] + s4[3]);
        sum += __shfl_xor(sum, 16);
        sum += __shfl_xor(sum, 32);
        float inv = 1.0f / sum;
        f32x4 o0 = zf, o1 = zf;
        o0 = __builtin_amdgcn_mfma_f32_16x16x32_bf16(vf[0],
                __builtin_shufflevector(ph[0], ph[1], 0,1,2,3,4,5,6,7), o0, 0,0,0);
        o1 = __builtin_amdgcn_mfma_f32_16x16x32_bf16(vf[1],
                __builtin_shufflevector(ph[2], ph[3], 0,1,2,3,4,5,6,7), o1, 0,0,0);
        o0 = __builtin_amdgcn_mfma_f32_16x16x32_bf16(vf[2],
                __builtin_shufflevector(ph[4], ph[5], 0,1,2,3,4,5,6,7), o0, 0,0,0);
        o1 = __builtin_amdgcn_mfma_f32_16x16x32_bf16(vf[3],
                __builtin_shufflevector(ph[6], ph[7], 0,1,2,3,4,5,6,7), o1, 0,0,0);
        o0 = __builtin_amdgcn_mfma_f32_16x16x32_bf16(vf[4],
                __builtin_shufflevector(ph[8], ph[9], 0,1,2,3,4,5,6,7), o0, 0,0,0);
        o1 = __builtin_amdgcn_mfma_f32_16x16x32_bf16(vf[5],
                __builtin_shufflevector(ph[10], z4,    0,1,2,3,4,5,6,7), o1, 0,0,0);
        f32x4 o = o0 + o1;
        int q = qc * 16 + li;
        if (q < NNODES) {
            bf16x4 ov = { (__bf16)(o[0] * inv), (__bf16)(o[1] * inv),
                          (__bf16)(o[2] * inv), (__bf16)(o[3] * inv) };
            *(bf16x4*)&ob[(size_t)q * CDIM + l4 * 4] = ov;
        }
    }
}

// ---------------------------------------------------------------- output projection
__global__ __launch_bounds__(512) void oproj_kernel(const __bf16* __restrict__ ows,
                                                    const float* __restrict__ Wo,
                                                    const float* __restrict__ bo,
                                                    float* __restrict__ out) {
    __shared__ __bf16 Wl[128 * 132];
    int t = threadIdx.x;
    int bt = blockIdx.x;
    #pragma unroll
    for (int i = 0; i < 8; ++i) {
        int idx = i * 512 + t;
        int r = idx >> 5, c = (idx & 31) * 4;
        f32x4 w4 = *(const f32x4*)&Wo[r * 128 + c];
        bf16x4 wb = { (__bf16)w4[0], (__bf16)w4[1], (__bf16)w4[2], (__bf16)w4[3] };
        *(bf16x4*)&Wl[r * 132 + c] = wb;
    }
    __syncthreads();

    int w = t >> 6, lane = t & 63, li = lane & 15, l4 = lane >> 4;
    const bf16x4 z4 = {(__bf16)0.f, (__bf16)0.f, (__bf16)0.f, (__bf16)0.f};
    for (int mt = 0; mt < 2; ++mt) {
        int tbase = mt * 128 + w * 16;
        if (tbase >= NNODES) break;
        int mrow = tbase + li;
        bool mvalid = mrow < NNODES;
        const __bf16* arow = ows + ((size_t)bt * NNODES + mrow) * CDIM;
        f32x4 acc[8] = {};
        #pragma unroll
        for (int kk = 0; kk < 4; ++kk) {
            int kb = kk * 32 + l4 * 4;
            bf16x4 a0 = mvalid ? *(const bf16x4*)(arow + kb)      : z4;
            bf16x4 a1 = mvalid ? *(const bf16x4*)(arow + kb + 16) : z4;
            bf16x8 a = __builtin_shufflevector(a0, a1, 0, 1, 2, 3, 4, 5, 6, 7);
            #pragma unroll
            for (int nt = 0; nt < 8; ++nt) {
                int c = nt * 16 + li;
                bf16x4 b0 = *(const bf16x4*)&Wl[c * 132 + kb];
                bf16x4 b1 = *(const bf16x4*)&Wl[c * 132 + kb + 16];
                bf16x8 b = __builtin_shufflevector(b0, b1, 0, 1, 2, 3, 4, 5, 6, 7);
                // swapped: col(li)=n, row(4*l4+r)=channel
                acc[nt] = __builtin_amdgcn_mfma_f32_16x16x32_bf16(b, a, acc[nt], 0, 0, 0);
            }
        }
        int n = tbase + li;
        if (n < NNODES) {
            float* orow = out + ((size_t)bt * NNODES + n) * CDIM;
            #pragma unroll
            for (int nt = 0; nt < 8; ++nt) {
                f32x4 b4 = *(const f32x4*)&bo[nt * 16 + l4 * 4];
                f32x4 o = acc[nt] + b4;
                // out is never re-read on-device: nontemporal keeps X L3-resident
                __builtin_nontemporal_store(o, (f32x4*)&orow[nt * 16 + l4 * 4]);
            }
        }
    }
}

// ---------------------------------------------------------------- launch
extern "C" void kernel_launch(void* const* d_in, const int* in_sizes, int n_in,
                              void* d_out, int out_size, void* d_ws, size_t ws_size,
                              hipStream_t stream) {
    const float* values = (const float*)d_in[0];
    const float* keys   = (const float*)d_in[1];
    const float* query  = (const float*)d_in[2];
    const float* Wv = (const float*)d_in[3];
    const float* bv = (const float*)d_in[4];
    const float* Wk = (const float*)d_in[5];
    const float* bk = (const float*)d_in[6];
    const float* Wq = (const float*)d_in[7];
    const float* bq = (const float*)d_in[8];
    const float* Wo = (const float*)d_in[9];
    const float* bo = (const float*)d_in[10];
    float* out = (float*)d_out;

    __bf16* qws = (__bf16*)d_ws;
    __bf16* kws = qws + QKV_ELEMS;
    __bf16* ows = kws + QKV_ELEMS;
    __bf16* vt  = (__bf16*)d_out;   // scratch inside d_out; consumed before oproj writes

    hipLaunchKernelGGL(qkv_kernel,  dim3(1536), dim3(512), 0, stream,
                       query, keys, values, Wq, Wk, Wv, bq, bk, bv, qws, kws, vt);
    hipLaunchKernelGGL(attn_kernel, dim3(2048), dim3(256), 0, stream, qws, kws, vt, ows);
    hipLaunchKernelGGL(oproj_kernel, dim3(512), dim3(512), 0, stream, ows, Wo, bo, out);
}